// Round 18
// baseline (430.475 us; speedup 1.0000x reference)
//
#include <hip/hip_runtime.h>
#include <hip/hip_bf16.h>
#include <cstdint>
#include <cstddef>

// ---------------------------------------------------------------------------
// Types & helpers
// ---------------------------------------------------------------------------
typedef _Float16 f16x8_t __attribute__((ext_vector_type(8)));
typedef float    f32x4_t __attribute__((ext_vector_type(4)));
typedef unsigned short u16x8_t __attribute__((ext_vector_type(8)));
typedef unsigned short u16x4_t __attribute__((ext_vector_type(4)));

__device__ __forceinline__ unsigned short f2h(float f) {
    return __builtin_bit_cast(unsigned short, (_Float16)f);
}
__device__ __forceinline__ float h2f(unsigned short h) {
    return (float)__builtin_bit_cast(_Float16, h);
}
__device__ __forceinline__ f16x8_t load_h8(const unsigned short* p) {
    u16x8_t r = *(const u16x8_t*)p;
    return __builtin_bit_cast(f16x8_t, r);
}

// ---------------------------------------------------------------------------
// Problem constants
// ---------------------------------------------------------------------------
#define BATCH 16
#define CFULL 512
#define CMID  256
#define HW    3136   // 56*56
#define WDIM  56

// LDS x-tile, k-major planes: 4 planes (one per kq group), each
// [348 positions x 16B]; wave quarter reads 256B contiguous.
#define PLANE_SH 2784             // shorts per plane (348 * 8)
#define LDS_SHORTS (4 * 2784)     // per buffer: 11136 shorts = 22272 B

// ---------------------------------------------------------------------------
// prep_tabs
// ---------------------------------------------------------------------------
__global__ void prep_tabs(const float* __restrict__ cscore,
                          const float* __restrict__ bn31, const float* __restrict__ bn33,
                          const float* __restrict__ bna1, const float* __restrict__ bna2,
                          int* __restrict__ pos_tab, float* __restrict__ scale_tab,
                          float* __restrict__ bnab)
{
    __shared__ float s[1024];
    int t = threadIdx.x;
    s[t] = cscore[t];
    __syncthreads();
    float sj = s[t];
    int cnt = 0;
    for (int k = 0; k < 1024; ++k) {
        float sk = s[k];
        cnt += (sk > sj) || (sk == sj && k < t);
    }
    pos_tab[t]   = (cnt < 512) ? cnt : -1;
    scale_tab[t] = 1.0f / (1.0f + expf(-sj));

    if (t < 256) {
        const float* srcs[4] = {bn31, bn33, bna1, bna2};
        #pragma unroll
        for (int q = 0; q < 4; ++q) {
            const float* sp = srcs[q];
            float g = sp[t], b = sp[256 + t], m = sp[512 + t], v = sp[768 + t];
            float a = g * rsqrtf(v + 1e-5f);
            bnab[q * 512 + t]       = a;
            bnab[q * 512 + 256 + t] = b - m * a;
        }
    }
}

// ---------------------------------------------------------------------------
// prep_weights: layouts
//   Wcat  [16 kch][768 oc][32]; Wmain [16 kch][9 tap][256 oc][32];
//   W33r  [ 8 kch][9 tap][256 oc][32]
// ---------------------------------------------------------------------------
__global__ void prep_weights(const float* __restrict__ w_main, const float* __restrict__ w_1x1,
                             const float* __restrict__ w31, const float* __restrict__ wa1,
                             const float* __restrict__ w33, const float* __restrict__ fw,
                             unsigned short* __restrict__ Wcat,
                             unsigned short* __restrict__ Wmain,
                             unsigned short* __restrict__ W33r)
{
    int i = blockIdx.x * 256 + threadIdx.x;
    if (i < 393216) {                         // Wcat: 768*512
        int row = i >> 9, c = i & 511;
        float v;
        if (row < 256)      v = w_1x1[row * 512 + c] * fw[1];
        else if (row < 512) v = w31[(row - 256) * 512 + c] * fw[2];
        else                v = wa1[(row - 512) * 512 + c] * fw[3];
        Wcat[((c >> 5) * 768 + row) * 32 + (c & 31)] = f2h(v);
    } else if (i < 393216 + 1179648) {        // Wmain: 256*9*512
        int j = i - 393216;
        int o = j / 4608, r = j % 4608, tap = r >> 9, c = r & 511;
        Wmain[(((c >> 5) * 9 + tap) * 256 + o) * 32 + (c & 31)] =
            f2h(w_main[(size_t)(o * 512 + c) * 9 + tap] * fw[0]);
    } else if (i < 2162688) {                 // W33r: 256*9*256
        int j = i - 1572864;
        int o = j / 2304, r = j % 2304, tap = r >> 8, c = r & 255;
        W33r[(((c >> 5) * 9 + tap) * 256 + o) * 32 + (c & 31)] =
            f2h(w33[(size_t)(o * 256 + c) * 9 + tap]);
    }
}

// ---------------------------------------------------------------------------
// transpose_x: NCHW f32 -> NHWC f16
// ---------------------------------------------------------------------------
__global__ void transpose_x(const float* __restrict__ x, unsigned short* __restrict__ xt)
{
    __shared__ unsigned short tile[64][65];
    int t = threadIdx.x;
    int hw0 = blockIdx.x * 64, c0 = blockIdx.y * 64, b = blockIdx.z;
    const float* xb = x + ((size_t)b * CFULL + c0) * HW + hw0;
    int hwL = t & 63, cL = t >> 6;
    #pragma unroll
    for (int i = 0; i < 16; ++i) {
        int c = cL + i * 4;
        tile[c][hwL] = f2h(xb[(size_t)c * HW + hwL]);
    }
    __syncthreads();
    int c8 = (t & 7) * 8, hw = t >> 3;
    #pragma unroll
    for (int i = 0; i < 2; ++i) {
        int hh = hw + i * 32;
        u16x8_t v;
        #pragma unroll
        for (int j = 0; j < 8; ++j) v[j] = tile[c8 + j][hh];
        *(u16x8_t*)(xt + ((size_t)b * HW + hw0 + hh) * CFULL + c0 + c8) = v;
    }
}

// ---------------------------------------------------------------------------
// conv_body: 2-barrier loop with k-major-plane LDS — fused 1x1 (MODE 1).
// ---------------------------------------------------------------------------
template<int CIN, int NTAP, int MODE>
__device__ __forceinline__ void conv_body(
    const unsigned short* __restrict__ X,
    const unsigned short* __restrict__ Wr,
    float* __restrict__ out,
    unsigned short* __restrict__ u_dst,
    unsigned short* __restrict__ avg_dst,
    const float* __restrict__ bnab,
    const int* __restrict__ pos_tab,
    const float* __restrict__ scale_tab,
    unsigned short* smem, int b, int ob, int pb)
{
    const int t    = threadIdx.x;
    const int lane = t & 63;
    const int wid  = t >> 6;
    const int wm = wid >> 1, wn = wid & 1;
    const int lr = lane & 15;
    const int ko = (lane >> 4) * 8;
    const int kqp = (lane >> 4) * PLANE_SH;
    const int row0 = pb * 4;

    const int o_wave = ob * 128 + wm * 64;
    const int p_wave = pb * 224 + wn * 112;

    int bofs[7];
    #pragma unroll
    for (int n = 0; n < 7; ++n) {
        int p = p_wave + n * 16 + lr;
        bofs[n] = kqp + ((p / WDIM - row0) * 58 + p % WDIM) * 8;
    }

    const int r_lo = (NTAP == 9) ? 0 : 1;
    const int nitems = ((NTAP == 9) ? 6 : 4) * 224;
    int  s_src[6];
    int  s_dst[6];
    bool s_val[6];
    #pragma unroll
    for (int i = 0; i < 6; ++i) {
        int idx = t + i * 256;
        bool act = idx < nitems;
        int r   = r_lo + idx / 224;
        int rm  = idx % 224;
        int col = rm >> 2, sub = rm & 3;
        int ir  = row0 + r - 1;
        s_val[i] = act && ((unsigned)ir < (unsigned)WDIM);
        s_src[i] = (ir * WDIM + col) * CIN + sub * 8;
        s_dst[i] = sub * PLANE_SH + (r * 58 + col + 1) * 8;
    }

    #pragma unroll
    for (int i = 0; i < 7; ++i) {
        int j = t + i * 256;
        if (j < LDS_SHORTS / 8)
            *(u16x8_t*)(smem + j * 8) = (u16x8_t){0, 0, 0, 0, 0, 0, 0, 0};
    }

    f32x4_t acc[4][7];
    #pragma unroll
    for (int m = 0; m < 4; ++m)
        #pragma unroll
        for (int n = 0; n < 7; ++n)
            acc[m][n] = (f32x4_t){0.f, 0.f, 0.f, 0.f};

    const int astep = (MODE == 1) ? 768 * 32 : 256 * 32;
    const unsigned short* am[4];
    #pragma unroll
    for (int m = 0; m < 4; ++m)
        am[m] = Wr + (size_t)(o_wave + m * 16 + lr) * 32 + ko;

    const unsigned short* xb = X + (size_t)b * HW * CIN;
    const int KCH = CIN / 32;

    for (int kch = 0; kch < KCH; ++kch) {
        __syncthreads();
        u16x8_t buf[6];
        #pragma unroll
        for (int i = 0; i < 6; ++i)
            if (s_val[i]) buf[i] = *(const u16x8_t*)(xb + s_src[i] + kch * 32);
        #pragma unroll
        for (int i = 0; i < 6; ++i)
            if (s_val[i]) *(u16x8_t*)(smem + s_dst[i]) = buf[i];
        __syncthreads();

        #pragma unroll
        for (int tap = 0; tap < NTAP; ++tap) {
            const int toff = (NTAP == 9) ? (((tap / 3) * 58 + tap % 3) * 8)
                                         : (59 * 8);
            f16x8_t af[4];
            #pragma unroll
            for (int m = 0; m < 4; ++m)
                af[m] = load_h8(am[m] + (size_t)(kch * NTAP + tap) * astep);
            f16x8_t bf[7];
            #pragma unroll
            for (int n = 0; n < 7; ++n)
                bf[n] = load_h8(smem + bofs[n] + toff);
            __builtin_amdgcn_s_setprio(1);
            #pragma unroll
            for (int m = 0; m < 4; ++m)
                #pragma unroll
                for (int n = 0; n < 7; ++n)
                    acc[m][n] = __builtin_amdgcn_mfma_f32_16x16x32_f16(af[m], bf[n], acc[m][n], 0, 0, 0);
            __builtin_amdgcn_s_setprio(0);
        }
    }

    const int fq = lane >> 4;
    const int seg = (MODE == 1) ? (ob >> 1) : 0;
    const bool bn_write = (MODE == 1) && (seg != 0);

    #pragma unroll
    for (int m = 0; m < 4; ++m) {
        const int orow = o_wave + m * 16 + fq * 4;
        #pragma unroll
        for (int n = 0; n < 7; ++n) {
            const int p = p_wave + n * 16 + lr;
            f32x4_t v = acc[m][n];
            if (bn_write) {
                const int lc0 = orow - seg * 256;
                const float* ab = (seg == 1) ? (bnab + 0 * 512) : (bnab + 2 * 512);
                unsigned short* dst = (seg == 1) ? u_dst : avg_dst;
                u16x4_t pk;
                #pragma unroll
                for (int j = 0; j < 4; ++j) {
                    float a = ab[lc0 + j], bb = ab[256 + lc0 + j];
                    pk[j] = f2h(a * v[j] + bb);
                }
                *(u16x4_t*)(dst + ((size_t)b * HW + p) * CMID + lc0) = pk;
            } else {
                const int cbase = (MODE == 0) ? 0 : ((MODE == 2) ? 512 : 256);
                #pragma unroll
                for (int j = 0; j < 4; ++j) {
                    int o = orow + j;
                    float val2 = v[j];
                    if (MODE == 2) val2 = bnab[512 + o] * val2 + bnab[512 + 256 + o];
                    int jc = cbase + o;
                    int pos = pos_tab[jc];
                    if (pos >= 0)
                        out[((size_t)b * CFULL + pos) * HW + p] = val2 * scale_tab[jc];
                }
            }
        }
    }
}

// ---------------------------------------------------------------------------
// conv_sched (r18): 9-phase schedule, BOTH operand streams prefetched:
//   - A: af[3][4] 3-slot rotation, depth-1: use = tap%3, fill = (tap+1)%3.
//     3 | 9 so the rotation is chunk-boundary-consistent (r17's &1 parity
//     broke across chunks because 9 is odd -> stale A -> absmax 7).
//   - B: bfr[2][7], re-primed to bfr[0] each chunk (parity safe), ds_reads
//     for tap t+1 issued BEFORE tap t's MFMA cluster; counted lgkmcnt(7)
//     hides the ~120cy LDS latency under the ~136cy MFMA cluster.
//   FIFO-verified waits (all loads wave-uniform; no SMEM in loop body):
//     vm:   taps 0-6 vmcnt(4); taps 7-8 vmcnt(10); chunk end vmcnt(4)
//     lgkm: taps 0-7 lgkmcnt(7); tap 8 lgkmcnt(0)
// ---------------------------------------------------------------------------
template<int CIN, int MODE>
__device__ __forceinline__ void conv_sched(
    const unsigned short* __restrict__ X,
    const unsigned short* __restrict__ Wr,
    float* __restrict__ out,
    const float* __restrict__ bnab,
    const int* __restrict__ pos_tab,
    const float* __restrict__ scale_tab,
    unsigned short* smem, int b, int ob, int pb)
{
    const int t    = threadIdx.x;
    const int lane = t & 63;
    const int wid  = t >> 6;
    const int wm = wid >> 1, wn = wid & 1;
    const int lr = lane & 15;
    const int ko = (lane >> 4) * 8;
    const int kqp = (lane >> 4) * PLANE_SH;
    const int row0 = pb * 4;

    const int o_wave = ob * 128 + wm * 64;
    const int p_wave = pb * 224 + wn * 112;

    int bofs[7];
    #pragma unroll
    for (int n = 0; n < 7; ++n) {
        int p = p_wave + n * 16 + lr;
        bofs[n] = kqp + ((p / WDIM - row0) * 58 + p % WDIM) * 8;
    }

    const int nitems = 6 * 224;
    const int dump_off = 2 * LDS_SHORTS + (t & 63) * 8 + (wid & 3) * 512;
    int s_src[6];
    int s_dst[6];
    #pragma unroll
    for (int i = 0; i < 6; ++i) {
        int idx = t + i * 256;
        int r   = idx / 224;
        int rm  = idx % 224;
        int col = rm >> 2, sub = rm & 3;
        int ir  = row0 + r - 1;
        bool v  = (idx < nitems) && ((unsigned)ir < (unsigned)WDIM);
        int ir_c = v ? ir : 0;
        s_src[i] = (ir_c * WDIM + col) * CIN + sub * 8;
        s_dst[i] = v ? (sub * PLANE_SH + (r * 58 + col + 1) * 8) : dump_off;
    }

    #pragma unroll
    for (int i = 0; i < 14; ++i) {
        int j = t + i * 256;
        if (j < 2 * LDS_SHORTS / 8)
            *(u16x8_t*)(smem + j * 8) = (u16x8_t){0, 0, 0, 0, 0, 0, 0, 0};
    }

    f32x4_t acc[4][7];
    #pragma unroll
    for (int m = 0; m < 4; ++m)
        #pragma unroll
        for (int n = 0; n < 7; ++n)
            acc[m][n] = (f32x4_t){0.f, 0.f, 0.f, 0.f};

    const int astep = 256 * 32;
    const unsigned short* am[4];
    #pragma unroll
    for (int m = 0; m < 4; ++m)
        am[m] = Wr + (size_t)(o_wave + m * 16 + lr) * 32 + ko;

    const unsigned short* xb = X + (size_t)b * HW * CIN;
    const int KCH = CIN / 32;
    const int NT = KCH * 9;

    f16x8_t af[3][4];       // A 3-slot rotation (depth-1, chunk-consistent)
    f16x8_t bfr[2][7];      // B double-buffer (re-primed per chunk)

    u16x8_t sbuf[6];
    __syncthreads();
    #pragma unroll
    for (int i = 0; i < 6; ++i)
        sbuf[i] = *(const u16x8_t*)(xb + s_src[i]);
    asm volatile("s_waitcnt vmcnt(0)" ::: "memory");
    #pragma unroll
    for (int i = 0; i < 6; ++i)
        *(u16x8_t*)(smem + s_dst[i]) = sbuf[i];
    #pragma unroll
    for (int m = 0; m < 4; ++m)
        af[0][m] = load_h8(am[m]);               // A(0): 4 vmem in flight
    asm volatile("s_waitcnt lgkmcnt(0)" ::: "memory");
    __builtin_amdgcn_s_barrier();                // buf0 ready

    #pragma unroll 1
    for (int kch = 0; kch < KCH; ++kch) {
        const unsigned short* rbuf = smem + (kch & 1) * LDS_SHORTS;
        unsigned short* wbuf = smem + ((kch + 1) & 1) * LDS_SHORTS;
        const int nk = (kch + 1 < KCH) ? (kch + 1) : 0;

        // prime B(0) of this chunk (tap0 toff = 0)
        #pragma unroll
        for (int n = 0; n < 7; ++n)
            bfr[0][n] = load_h8(rbuf + bofs[n]);

        #pragma unroll
        for (int tap = 0; tap < 9; ++tap) {
            const int fillA = (tap + 1) % 3;     // static under unroll
            const int useA  = tap % 3;
            const int useB  = tap & 1;
            // issue A(t+1) — wraps to dummy 0 at the very end (uniform)
            int kt = kch * 9 + tap + 1;
            if (kt >= NT) kt = 0;
            #pragma unroll
            for (int m = 0; m < 4; ++m)
                af[fillA][m] = load_h8(am[m] + (size_t)kt * astep);
            // staging burst for chunk k+1 at phase 7
            if (tap == 7) {
                #pragma unroll
                for (int i = 0; i < 6; ++i)
                    sbuf[i] = *(const u16x8_t*)(xb + s_src[i] + nk * 32);
            }
            // issue B(t+1) ds_reads (retire under this tap's MFMAs)
            if (tap < 8) {
                const int toff1 = (((tap + 1) / 3) * 58 + (tap + 1) % 3) * 8;
                #pragma unroll
                for (int n = 0; n < 7; ++n)
                    bfr[(tap + 1) & 1][n] = load_h8(rbuf + bofs[n] + toff1);
            }
            // counted waits: A(t), B(t) done; A(t+1), B(t+1), staging in flight
            if (tap < 7)
                asm volatile("s_waitcnt vmcnt(4) lgkmcnt(7)" ::: "memory");
            else if (tap == 7)
                asm volatile("s_waitcnt vmcnt(10) lgkmcnt(7)" ::: "memory");
            else
                asm volatile("s_waitcnt vmcnt(10) lgkmcnt(0)" ::: "memory");
            __builtin_amdgcn_sched_barrier(0);
            __builtin_amdgcn_s_setprio(1);
            #pragma unroll
            for (int m = 0; m < 4; ++m)
                #pragma unroll
                for (int n = 0; n < 7; ++n)
                    acc[m][n] = __builtin_amdgcn_mfma_f32_16x16x32_f16(af[useA][m], bfr[useB][n], acc[m][n], 0, 0, 0);
            __builtin_amdgcn_s_setprio(0);
            __builtin_amdgcn_sched_barrier(0);
        }

        // chunk end: drain staging (next chunk's A(0) stays in flight)
        asm volatile("s_waitcnt vmcnt(4)" ::: "memory");
        #pragma unroll
        for (int i = 0; i < 6; ++i)
            *(u16x8_t*)(wbuf + s_dst[i]) = sbuf[i];
        asm volatile("s_waitcnt lgkmcnt(0)" ::: "memory");
        __builtin_amdgcn_s_barrier();
    }

    const int fq = lane >> 4;
    #pragma unroll
    for (int m = 0; m < 4; ++m) {
        const int orow = o_wave + m * 16 + fq * 4;
        #pragma unroll
        for (int n = 0; n < 7; ++n) {
            const int p = p_wave + n * 16 + lr;
            f32x4_t v = acc[m][n];
            const int cbase = (MODE == 0) ? 0 : 512;
            #pragma unroll
            for (int j = 0; j < 4; ++j) {
                int o = orow + j;
                float val2 = v[j];
                if (MODE == 2) val2 = bnab[512 + o] * val2 + bnab[512 + 256 + o];
                int jc = cbase + o;
                int pos = pos_tab[jc];
                if (pos >= 0)
                    out[((size_t)b * CFULL + pos) * HW + p] = val2 * scale_tab[jc];
            }
        }
    }
}

// ---------------------------------------------------------------------------
// K1: fused 1x1 (all 16 batches) + main 3x3 for batches 0..7 (longs FIRST).
//   1568 blocks: xcd = id&7, slot = id>>3 (0..195):
//     slot < 28 : main, b = xcd, u = slot
//     else      : 1x1,  g = slot-28, b = xcd + 8*(g/84), u = g%84
// ---------------------------------------------------------------------------
__global__ __launch_bounds__(256, 2)
void convK1(const unsigned short* __restrict__ X,
            const unsigned short* __restrict__ Wmain,
            const unsigned short* __restrict__ Wcat,
            float* __restrict__ out,
            unsigned short* __restrict__ u_dst,
            unsigned short* __restrict__ avg_dst,
            const float* __restrict__ bnab,
            const int* __restrict__ pos_tab,
            const float* __restrict__ scale_tab)
{
    __shared__ unsigned short smem[2 * LDS_SHORTS + 2048];
    const int id = blockIdx.x;
    const int xcd = id & 7, slot = id >> 3;
    if (slot < 28) {
        conv_sched<512, 0>(X, Wmain, out, bnab, pos_tab, scale_tab,
                           smem, xcd, slot / 14, slot % 14);
    } else {
        const int g = slot - 28;
        const int b = xcd + 8 * (g / 84);
        const int u = g % 84;
        conv_body<512, 1, 1>(X, Wcat, out, u_dst, avg_dst, bnab,
                             pos_tab, scale_tab, smem, b, u / 14, u % 14);
    }
}

// ---------------------------------------------------------------------------
// K2: main 3x3 (batches 8..15) + mid 3x3 (all 16) interleaved 1:2, then
//   separable row-pool (one block per (b,h) row).
//   1568 blocks: xcd = id&7, slot = id>>3 (0..195):
//     slot < 84 : m = slot/3, r = slot%3; ob=m/14, pb=m%14
//                 r==0 -> main b=8+xcd; r==1 -> mid b=xcd; r==2 -> mid b=xcd+8
//     else      : pool, q = slot-84 (0..111): b = xcd + 8*(q/56), h = q%56
// ---------------------------------------------------------------------------
__global__ __launch_bounds__(256, 2)
void convK2(const unsigned short* __restrict__ X,
            const unsigned short* __restrict__ Wmain,
            const unsigned short* __restrict__ U,
            const unsigned short* __restrict__ W33r,
            const unsigned short* __restrict__ avgin,
            float* __restrict__ out,
            const float* __restrict__ bnab,
            const int* __restrict__ pos_tab,
            const float* __restrict__ scale_tab)
{
    __shared__ unsigned short smem[2 * LDS_SHORTS + 2048];
    const int id = blockIdx.x;
    const int xcd = id & 7, slot = id >> 3;
    if (slot < 84) {
        const int m = slot / 3, r = slot % 3;
        const int ob = m / 14, pb = m % 14;
        if (r == 0)
            conv_sched<512, 0>(X, Wmain, out, bnab, pos_tab, scale_tab,
                               smem, 8 + xcd, ob, pb);
        else
            conv_sched<256, 2>(U, W33r, out, bnab, pos_tab, scale_tab,
                               smem, (r == 1) ? xcd : (xcd + 8), ob, pb);
    } else {
        const int q = slot - 84;
        const int b = xcd + 8 * (q / 56);
        const int h = q % 56;
        const int t = threadIdx.x;
        const int c0 = (t & 31) * 8;
        const int ws = t >> 5;                 // 0..7, covers w = ws*7..ws*7+6
        const float* ab2 = bnab + 3 * 512;
        const unsigned short* ab_base = avgin + (size_t)b * HW * CMID;

        // vertical 3-sum into LDS (f16)
        #pragma unroll
        for (int i = 0; i < 7; ++i) {
            int w = ws * 7 + i;
            float s[8];
            #pragma unroll
            for (int j = 0; j < 8; ++j) s[j] = 0.f;
            #pragma unroll
            for (int dh = -1; dh <= 1; ++dh) {
                int hh = h + dh;
                if ((unsigned)hh >= (unsigned)WDIM) continue;
                u16x8_t v = *(const u16x8_t*)(ab_base + (size_t)(hh * WDIM + w) * CMID + c0);
                #pragma unroll
                for (int j = 0; j < 8; ++j) s[j] += h2f(v[j]);
            }
            u16x8_t pk;
            #pragma unroll
            for (int j = 0; j < 8; ++j) pk[j] = f2h(s[j]);
            *(u16x8_t*)(smem + w * CMID + c0) = pk;
        }
        __syncthreads();

        // horizontal 3-sum + bn + scatter
        #pragma unroll
        for (int i = 0; i < 7; ++i) {
            int w = ws * 7 + i;
            float s[8];
            #pragma unroll
            for (int j = 0; j < 8; ++j) s[j] = 0.f;
            #pragma unroll
            for (int dw = -1; dw <= 1; ++dw) {
                int ww = w + dw;
                if ((unsigned)ww >= (unsigned)WDIM) continue;
                u16x8_t v = *(const u16x8_t*)(smem + ww * CMID + c0);
                #pragma unroll
                for (int j = 0; j < 8; ++j) s[j] += h2f(v[j]);
            }
            const int p = h * WDIM + w;
            #pragma unroll
            for (int j = 0; j < 8; ++j) {
                int c = c0 + j;
                int jc = 768 + c;
                int pos = pos_tab[jc];
                if (pos >= 0) {
                    float val = (s[j] * (1.f / 9.f)) * ab2[c] + ab2[256 + c];
                    out[((size_t)b * CFULL + pos) * HW + p] = val * scale_tab[jc];
                }
            }
        }
    }
}

// ---------------------------------------------------------------------------
// Launch
// ---------------------------------------------------------------------------
extern "C" void kernel_launch(void* const* d_in, const int* in_sizes, int n_in,
                              void* d_out, int out_size, void* d_ws, size_t ws_size,
                              hipStream_t stream) {
    (void)in_sizes; (void)n_in; (void)out_size; (void)ws_size;
    const float* x      = (const float*)d_in[0];
    const float* w_main = (const float*)d_in[1];
    const float* w_1x1  = (const float*)d_in[2];
    const float* w31    = (const float*)d_in[3];
    const float* bn31   = (const float*)d_in[4];
    const float* w33    = (const float*)d_in[5];
    const float* bn33   = (const float*)d_in[6];
    const float* wa1    = (const float*)d_in[7];
    const float* bna1   = (const float*)d_in[8];
    const float* bna2   = (const float*)d_in[9];
    const float* fw     = (const float*)d_in[10];
    const float* cscore = (const float*)d_in[11];
    float* out = (float*)d_out;

    char* ws = (char*)d_ws;
    unsigned short* x_nhwc = (unsigned short*)(ws);                 // 51,380,224 B
    unsigned short* u_nhwc = (unsigned short*)(ws + 51380224);      // 25,690,112 B
    unsigned short* avgin  = (unsigned short*)(ws + 77070336);      // 25,690,112 B
    unsigned short* Wcat   = (unsigned short*)(ws + 102760448);     //    786,432 B
    unsigned short* Wmain  = (unsigned short*)(ws + 103546880);     //  2,359,296 B
    unsigned short* W33r   = (unsigned short*)(ws + 105906176);     //  1,179,648 B
    float*          bnab   = (float*)        (ws + 107085824);      //      8,192 B
    int*            pos_tab= (int*)          (ws + 107094016);      //      4,096 B
    float*          scl_tab= (float*)        (ws + 107098112);      //      4,096 B

    dim3 blk(256);

    prep_tabs<<<dim3(1), dim3(1024), 0, stream>>>(cscore, bn31, bn33, bna1, bna2,
                                                  pos_tab, scl_tab, bnab);
    prep_weights<<<dim3(8448), blk, 0, stream>>>(w_main, w_1x1, w31, wa1, w33, fw,
                                                 Wcat, Wmain, W33r);
    transpose_x<<<dim3(49, 8, 16), blk, 0, stream>>>(x, x_nhwc);

    // K1: fused 1x1 (all batches) + main conv batches 0..7
    convK1<<<dim3(1568), blk, 0, stream>>>(x_nhwc, Wmain, Wcat, out,
                                           u_nhwc, avgin, bnab, pos_tab, scl_tab);

    // K2: main conv batches 8..15 + mid conv (all) + separable row-pool
    convK2<<<dim3(1568), blk, 0, stream>>>(x_nhwc, Wmain, u_nhwc, W33r, avgin,
                                           out, bnab, pos_tab, scl_tab);
}

// Round 19
// 387.375 us; speedup vs baseline: 1.1113x; 1.1113x over previous
//
#include <hip/hip_runtime.h>
#include <hip/hip_bf16.h>
#include <cstdint>
#include <cstddef>

// ---------------------------------------------------------------------------
// Types & helpers
// ---------------------------------------------------------------------------
typedef _Float16 f16x8_t __attribute__((ext_vector_type(8)));
typedef float    f32x4_t __attribute__((ext_vector_type(4)));
typedef unsigned short u16x8_t __attribute__((ext_vector_type(8)));
typedef unsigned short u16x4_t __attribute__((ext_vector_type(4)));

__device__ __forceinline__ unsigned short f2h(float f) {
    return __builtin_bit_cast(unsigned short, (_Float16)f);
}
__device__ __forceinline__ float h2f(unsigned short h) {
    return (float)__builtin_bit_cast(_Float16, h);
}
__device__ __forceinline__ f16x8_t load_h8(const unsigned short* p) {
    u16x8_t r = *(const u16x8_t*)p;
    return __builtin_bit_cast(f16x8_t, r);
}

// ---------------------------------------------------------------------------
// Problem constants
// ---------------------------------------------------------------------------
#define BATCH 16
#define CFULL 512
#define CMID  256
#define HW    3136   // 56*56
#define WDIM  56

// LDS x-tile, k-major planes: 4 planes (one per kq group), each
// [348 positions x 16B]; wave quarter reads 256B contiguous.
#define PLANE_SH 2784             // shorts per plane (348 * 8)
#define LDS_SHORTS (4 * 2784)     // per buffer: 11136 shorts = 22272 B

// ---------------------------------------------------------------------------
// prep_tabs
// ---------------------------------------------------------------------------
__global__ void prep_tabs(const float* __restrict__ cscore,
                          const float* __restrict__ bn31, const float* __restrict__ bn33,
                          const float* __restrict__ bna1, const float* __restrict__ bna2,
                          int* __restrict__ pos_tab, float* __restrict__ scale_tab,
                          float* __restrict__ bnab)
{
    __shared__ float s[1024];
    int t = threadIdx.x;
    s[t] = cscore[t];
    __syncthreads();
    float sj = s[t];
    int cnt = 0;
    for (int k = 0; k < 1024; ++k) {
        float sk = s[k];
        cnt += (sk > sj) || (sk == sj && k < t);
    }
    pos_tab[t]   = (cnt < 512) ? cnt : -1;
    scale_tab[t] = 1.0f / (1.0f + expf(-sj));

    if (t < 256) {
        const float* srcs[4] = {bn31, bn33, bna1, bna2};
        #pragma unroll
        for (int q = 0; q < 4; ++q) {
            const float* sp = srcs[q];
            float g = sp[t], b = sp[256 + t], m = sp[512 + t], v = sp[768 + t];
            float a = g * rsqrtf(v + 1e-5f);
            bnab[q * 512 + t]       = a;
            bnab[q * 512 + 256 + t] = b - m * a;
        }
    }
}

// ---------------------------------------------------------------------------
// prep_weights: layouts
//   Wcat  [16 kch][768 oc][32]; Wmain [16 kch][9 tap][256 oc][32];
//   W33r  [ 8 kch][9 tap][256 oc][32]
// ---------------------------------------------------------------------------
__global__ void prep_weights(const float* __restrict__ w_main, const float* __restrict__ w_1x1,
                             const float* __restrict__ w31, const float* __restrict__ wa1,
                             const float* __restrict__ w33, const float* __restrict__ fw,
                             unsigned short* __restrict__ Wcat,
                             unsigned short* __restrict__ Wmain,
                             unsigned short* __restrict__ W33r)
{
    int i = blockIdx.x * 256 + threadIdx.x;
    if (i < 393216) {                         // Wcat: 768*512
        int row = i >> 9, c = i & 511;
        float v;
        if (row < 256)      v = w_1x1[row * 512 + c] * fw[1];
        else if (row < 512) v = w31[(row - 256) * 512 + c] * fw[2];
        else                v = wa1[(row - 512) * 512 + c] * fw[3];
        Wcat[((c >> 5) * 768 + row) * 32 + (c & 31)] = f2h(v);
    } else if (i < 393216 + 1179648) {        // Wmain: 256*9*512
        int j = i - 393216;
        int o = j / 4608, r = j % 4608, tap = r >> 9, c = r & 511;
        Wmain[(((c >> 5) * 9 + tap) * 256 + o) * 32 + (c & 31)] =
            f2h(w_main[(size_t)(o * 512 + c) * 9 + tap] * fw[0]);
    } else if (i < 2162688) {                 // W33r: 256*9*256
        int j = i - 1572864;
        int o = j / 2304, r = j % 2304, tap = r >> 8, c = r & 255;
        W33r[(((c >> 5) * 9 + tap) * 256 + o) * 32 + (c & 31)] =
            f2h(w33[(size_t)(o * 256 + c) * 9 + tap]);
    }
}

// ---------------------------------------------------------------------------
// transpose_x: NCHW f32 -> NHWC f16
// ---------------------------------------------------------------------------
__global__ void transpose_x(const float* __restrict__ x, unsigned short* __restrict__ xt)
{
    __shared__ unsigned short tile[64][65];
    int t = threadIdx.x;
    int hw0 = blockIdx.x * 64, c0 = blockIdx.y * 64, b = blockIdx.z;
    const float* xb = x + ((size_t)b * CFULL + c0) * HW + hw0;
    int hwL = t & 63, cL = t >> 6;
    #pragma unroll
    for (int i = 0; i < 16; ++i) {
        int c = cL + i * 4;
        tile[c][hwL] = f2h(xb[(size_t)c * HW + hwL]);
    }
    __syncthreads();
    int c8 = (t & 7) * 8, hw = t >> 3;
    #pragma unroll
    for (int i = 0; i < 2; ++i) {
        int hh = hw + i * 32;
        u16x8_t v;
        #pragma unroll
        for (int j = 0; j < 8; ++j) v[j] = tile[c8 + j][hh];
        *(u16x8_t*)(xt + ((size_t)b * HW + hw0 + hh) * CFULL + c0 + c8) = v;
    }
}

// ---------------------------------------------------------------------------
// conv_body: 2-barrier loop with k-major-plane LDS — fused 1x1 (MODE 1).
// ---------------------------------------------------------------------------
template<int CIN, int NTAP, int MODE>
__device__ __forceinline__ void conv_body(
    const unsigned short* __restrict__ X,
    const unsigned short* __restrict__ Wr,
    float* __restrict__ out,
    unsigned short* __restrict__ u_dst,
    unsigned short* __restrict__ avg_dst,
    const float* __restrict__ bnab,
    const int* __restrict__ pos_tab,
    const float* __restrict__ scale_tab,
    unsigned short* smem, int b, int ob, int pb)
{
    const int t    = threadIdx.x;
    const int lane = t & 63;
    const int wid  = t >> 6;
    const int wm = wid >> 1, wn = wid & 1;
    const int lr = lane & 15;
    const int ko = (lane >> 4) * 8;
    const int kqp = (lane >> 4) * PLANE_SH;
    const int row0 = pb * 4;

    const int o_wave = ob * 128 + wm * 64;
    const int p_wave = pb * 224 + wn * 112;

    int bofs[7];
    #pragma unroll
    for (int n = 0; n < 7; ++n) {
        int p = p_wave + n * 16 + lr;
        bofs[n] = kqp + ((p / WDIM - row0) * 58 + p % WDIM) * 8;
    }

    const int r_lo = (NTAP == 9) ? 0 : 1;
    const int nitems = ((NTAP == 9) ? 6 : 4) * 224;
    int  s_src[6];
    int  s_dst[6];
    bool s_val[6];
    #pragma unroll
    for (int i = 0; i < 6; ++i) {
        int idx = t + i * 256;
        bool act = idx < nitems;
        int r   = r_lo + idx / 224;
        int rm  = idx % 224;
        int col = rm >> 2, sub = rm & 3;
        int ir  = row0 + r - 1;
        s_val[i] = act && ((unsigned)ir < (unsigned)WDIM);
        s_src[i] = (ir * WDIM + col) * CIN + sub * 8;
        s_dst[i] = sub * PLANE_SH + (r * 58 + col + 1) * 8;
    }

    #pragma unroll
    for (int i = 0; i < 7; ++i) {
        int j = t + i * 256;
        if (j < LDS_SHORTS / 8)
            *(u16x8_t*)(smem + j * 8) = (u16x8_t){0, 0, 0, 0, 0, 0, 0, 0};
    }

    f32x4_t acc[4][7];
    #pragma unroll
    for (int m = 0; m < 4; ++m)
        #pragma unroll
        for (int n = 0; n < 7; ++n)
            acc[m][n] = (f32x4_t){0.f, 0.f, 0.f, 0.f};

    const int astep = (MODE == 1) ? 768 * 32 : 256 * 32;
    const unsigned short* am[4];
    #pragma unroll
    for (int m = 0; m < 4; ++m)
        am[m] = Wr + (size_t)(o_wave + m * 16 + lr) * 32 + ko;

    const unsigned short* xb = X + (size_t)b * HW * CIN;
    const int KCH = CIN / 32;

    for (int kch = 0; kch < KCH; ++kch) {
        __syncthreads();
        u16x8_t buf[6];
        #pragma unroll
        for (int i = 0; i < 6; ++i)
            if (s_val[i]) buf[i] = *(const u16x8_t*)(xb + s_src[i] + kch * 32);
        #pragma unroll
        for (int i = 0; i < 6; ++i)
            if (s_val[i]) *(u16x8_t*)(smem + s_dst[i]) = buf[i];
        __syncthreads();

        #pragma unroll
        for (int tap = 0; tap < NTAP; ++tap) {
            const int toff = (NTAP == 9) ? (((tap / 3) * 58 + tap % 3) * 8)
                                         : (59 * 8);
            f16x8_t af[4];
            #pragma unroll
            for (int m = 0; m < 4; ++m)
                af[m] = load_h8(am[m] + (size_t)(kch * NTAP + tap) * astep);
            f16x8_t bf[7];
            #pragma unroll
            for (int n = 0; n < 7; ++n)
                bf[n] = load_h8(smem + bofs[n] + toff);
            __builtin_amdgcn_s_setprio(1);
            #pragma unroll
            for (int m = 0; m < 4; ++m)
                #pragma unroll
                for (int n = 0; n < 7; ++n)
                    acc[m][n] = __builtin_amdgcn_mfma_f32_16x16x32_f16(af[m], bf[n], acc[m][n], 0, 0, 0);
            __builtin_amdgcn_s_setprio(0);
        }
    }

    const int fq = lane >> 4;
    const int seg = (MODE == 1) ? (ob >> 1) : 0;
    const bool bn_write = (MODE == 1) && (seg != 0);

    #pragma unroll
    for (int m = 0; m < 4; ++m) {
        const int orow = o_wave + m * 16 + fq * 4;
        #pragma unroll
        for (int n = 0; n < 7; ++n) {
            const int p = p_wave + n * 16 + lr;
            f32x4_t v = acc[m][n];
            if (bn_write) {
                const int lc0 = orow - seg * 256;
                const float* ab = (seg == 1) ? (bnab + 0 * 512) : (bnab + 2 * 512);
                unsigned short* dst = (seg == 1) ? u_dst : avg_dst;
                u16x4_t pk;
                #pragma unroll
                for (int j = 0; j < 4; ++j) {
                    float a = ab[lc0 + j], bb = ab[256 + lc0 + j];
                    pk[j] = f2h(a * v[j] + bb);
                }
                *(u16x4_t*)(dst + ((size_t)b * HW + p) * CMID + lc0) = pk;
            } else {
                const int cbase = (MODE == 0) ? 0 : ((MODE == 2) ? 512 : 256);
                #pragma unroll
                for (int j = 0; j < 4; ++j) {
                    int o = orow + j;
                    float val2 = v[j];
                    if (MODE == 2) val2 = bnab[512 + o] * val2 + bnab[512 + 256 + o];
                    int jc = cbase + o;
                    int pos = pos_tab[jc];
                    if (pos >= 0)
                        out[((size_t)b * CFULL + pos) * HW + p] = val2 * scale_tab[jc];
                }
            }
        }
    }
}

// ---------------------------------------------------------------------------
// conv_sched: 9-phase counted-vmcnt schedule + plane LDS.
// ---------------------------------------------------------------------------
template<int CIN, int MODE>
__device__ __forceinline__ void conv_sched(
    const unsigned short* __restrict__ X,
    const unsigned short* __restrict__ Wr,
    float* __restrict__ out,
    const float* __restrict__ bnab,
    const int* __restrict__ pos_tab,
    const float* __restrict__ scale_tab,
    unsigned short* smem, int b, int ob, int pb)
{
    const int t    = threadIdx.x;
    const int lane = t & 63;
    const int wid  = t >> 6;
    const int wm = wid >> 1, wn = wid & 1;
    const int lr = lane & 15;
    const int ko = (lane >> 4) * 8;
    const int kqp = (lane >> 4) * PLANE_SH;
    const int row0 = pb * 4;

    const int o_wave = ob * 128 + wm * 64;
    const int p_wave = pb * 224 + wn * 112;

    int bofs[7];
    #pragma unroll
    for (int n = 0; n < 7; ++n) {
        int p = p_wave + n * 16 + lr;
        bofs[n] = kqp + ((p / WDIM - row0) * 58 + p % WDIM) * 8;
    }

    const int nitems = 6 * 224;
    const int dump_off = 2 * LDS_SHORTS + (t & 63) * 8 + (wid & 3) * 512;
    int s_src[6];
    int s_dst[6];
    #pragma unroll
    for (int i = 0; i < 6; ++i) {
        int idx = t + i * 256;
        int r   = idx / 224;
        int rm  = idx % 224;
        int col = rm >> 2, sub = rm & 3;
        int ir  = row0 + r - 1;
        bool v  = (idx < nitems) && ((unsigned)ir < (unsigned)WDIM);
        int ir_c = v ? ir : 0;
        s_src[i] = (ir_c * WDIM + col) * CIN + sub * 8;
        s_dst[i] = v ? (sub * PLANE_SH + (r * 58 + col + 1) * 8) : dump_off;
    }

    #pragma unroll
    for (int i = 0; i < 14; ++i) {
        int j = t + i * 256;
        if (j < 2 * LDS_SHORTS / 8)
            *(u16x8_t*)(smem + j * 8) = (u16x8_t){0, 0, 0, 0, 0, 0, 0, 0};
    }

    f32x4_t acc[4][7];
    #pragma unroll
    for (int m = 0; m < 4; ++m)
        #pragma unroll
        for (int n = 0; n < 7; ++n)
            acc[m][n] = (f32x4_t){0.f, 0.f, 0.f, 0.f};

    const int astep = 256 * 32;
    const unsigned short* am[4];
    #pragma unroll
    for (int m = 0; m < 4; ++m)
        am[m] = Wr + (size_t)(o_wave + m * 16 + lr) * 32 + ko;

    const unsigned short* xb = X + (size_t)b * HW * CIN;
    const int KCH = CIN / 32;
    const int NT = KCH * 9;

    f16x8_t af[3][4];

    u16x8_t sbuf[6];
    __syncthreads();
    #pragma unroll
    for (int i = 0; i < 6; ++i)
        sbuf[i] = *(const u16x8_t*)(xb + s_src[i]);
    asm volatile("s_waitcnt vmcnt(0)" ::: "memory");
    #pragma unroll
    for (int i = 0; i < 6; ++i)
        *(u16x8_t*)(smem + s_dst[i]) = sbuf[i];
    #pragma unroll
    for (int m = 0; m < 4; ++m)
        af[0][m] = load_h8(am[m]);
    #pragma unroll
    for (int m = 0; m < 4; ++m)
        af[1][m] = load_h8(am[m] + (size_t)1 * astep);
    asm volatile("s_waitcnt lgkmcnt(0)" ::: "memory");
    __builtin_amdgcn_s_barrier();

    #pragma unroll 1
    for (int kch = 0; kch < KCH; ++kch) {
        const unsigned short* rbuf = smem + (kch & 1) * LDS_SHORTS;
        unsigned short* wbuf = smem + ((kch + 1) & 1) * LDS_SHORTS;
        const int nk = (kch + 1 < KCH) ? (kch + 1) : 0;

        #pragma unroll
        for (int tap = 0; tap < 9; ++tap) {
            const int fill = (tap + 2) % 3;
            const int use  = tap % 3;
            int kt = kch * 9 + tap + 2;
            if (kt >= NT) kt -= NT;
            #pragma unroll
            for (int m = 0; m < 4; ++m)
                af[fill][m] = load_h8(am[m] + (size_t)kt * astep);
            if (tap == 7) {
                #pragma unroll
                for (int i = 0; i < 6; ++i)
                    sbuf[i] = *(const u16x8_t*)(xb + s_src[i] + nk * 32);
            }
            const int toff = ((tap / 3) * 58 + tap % 3) * 8;
            f16x8_t bf[7];
            #pragma unroll
            for (int n = 0; n < 7; ++n)
                bf[n] = load_h8(rbuf + bofs[n] + toff);
            if (tap < 7)
                asm volatile("s_waitcnt vmcnt(8) lgkmcnt(0)" ::: "memory");
            else
                asm volatile("s_waitcnt vmcnt(14) lgkmcnt(0)" ::: "memory");
            __builtin_amdgcn_sched_barrier(0);
            __builtin_amdgcn_s_setprio(1);
            #pragma unroll
            for (int m = 0; m < 4; ++m)
                #pragma unroll
                for (int n = 0; n < 7; ++n)
                    acc[m][n] = __builtin_amdgcn_mfma_f32_16x16x32_f16(af[use][m], bf[n], acc[m][n], 0, 0, 0);
            __builtin_amdgcn_s_setprio(0);
            __builtin_amdgcn_sched_barrier(0);
        }

        asm volatile("s_waitcnt vmcnt(4)" ::: "memory");
        #pragma unroll
        for (int i = 0; i < 6; ++i)
            *(u16x8_t*)(wbuf + s_dst[i]) = sbuf[i];
        asm volatile("s_waitcnt lgkmcnt(0)" ::: "memory");
        __builtin_amdgcn_s_barrier();
    }

    const int fq = lane >> 4;
    #pragma unroll
    for (int m = 0; m < 4; ++m) {
        const int orow = o_wave + m * 16 + fq * 4;
        #pragma unroll
        for (int n = 0; n < 7; ++n) {
            const int p = p_wave + n * 16 + lr;
            f32x4_t v = acc[m][n];
            const int cbase = (MODE == 0) ? 0 : 512;
            #pragma unroll
            for (int j = 0; j < 4; ++j) {
                int o = orow + j;
                float val2 = v[j];
                if (MODE == 2) val2 = bnab[512 + o] * val2 + bnab[512 + 256 + o];
                int jc = cbase + o;
                int pos = pos_tab[jc];
                if (pos >= 0)
                    out[((size_t)b * CFULL + pos) * HW + p] = val2 * scale_tab[jc];
            }
        }
    }
}

// ---------------------------------------------------------------------------
// K1: fused 1x1 (all 16 batches) + main 3x3 for batches 0..7 (longs FIRST).
//   1568 blocks: xcd = id&7, slot = id>>3 (0..195):
//     slot < 28 : main, b = xcd, u = slot
//     else      : 1x1,  g = slot-28, b = xcd + 8*(g/84), u = g%84
// ---------------------------------------------------------------------------
__global__ __launch_bounds__(256, 2)
void convK1(const unsigned short* __restrict__ X,
            const unsigned short* __restrict__ Wmain,
            const unsigned short* __restrict__ Wcat,
            float* __restrict__ out,
            unsigned short* __restrict__ u_dst,
            unsigned short* __restrict__ avg_dst,
            const float* __restrict__ bnab,
            const int* __restrict__ pos_tab,
            const float* __restrict__ scale_tab)
{
    __shared__ unsigned short smem[2 * LDS_SHORTS + 2048];
    const int id = blockIdx.x;
    const int xcd = id & 7, slot = id >> 3;
    if (slot < 28) {
        conv_sched<512, 0>(X, Wmain, out, bnab, pos_tab, scale_tab,
                           smem, xcd, slot / 14, slot % 14);
    } else {
        const int g = slot - 28;
        const int b = xcd + 8 * (g / 84);
        const int u = g % 84;
        conv_body<512, 1, 1>(X, Wcat, out, u_dst, avg_dst, bnab,
                             pos_tab, scale_tab, smem, b, u / 14, u % 14);
    }
}

// ---------------------------------------------------------------------------
// K2: main 3x3 (batches 8..15) + mid 3x3 (all 16) interleaved 1:2, then
//   separable row-pool (one block per (b,h) row).
//   1568 blocks: xcd = id&7, slot = id>>3 (0..195):
//     slot < 84 : m = slot/3, r = slot%3; ob=m/14, pb=m%14
//                 r==0 -> main b=8+xcd; r==1 -> mid b=xcd; r==2 -> mid b=xcd+8
//     else      : pool, q = slot-84 (0..111): b = xcd + 8*(q/56), h = q%56
// ---------------------------------------------------------------------------
__global__ __launch_bounds__(256, 2)
void convK2(const unsigned short* __restrict__ X,
            const unsigned short* __restrict__ Wmain,
            const unsigned short* __restrict__ U,
            const unsigned short* __restrict__ W33r,
            const unsigned short* __restrict__ avgin,
            float* __restrict__ out,
            const float* __restrict__ bnab,
            const int* __restrict__ pos_tab,
            const float* __restrict__ scale_tab)
{
    __shared__ unsigned short smem[2 * LDS_SHORTS + 2048];
    const int id = blockIdx.x;
    const int xcd = id & 7, slot = id >> 3;
    if (slot < 84) {
        const int m = slot / 3, r = slot % 3;
        const int ob = m / 14, pb = m % 14;
        if (r == 0)
            conv_sched<512, 0>(X, Wmain, out, bnab, pos_tab, scale_tab,
                               smem, 8 + xcd, ob, pb);
        else
            conv_sched<256, 2>(U, W33r, out, bnab, pos_tab, scale_tab,
                               smem, (r == 1) ? xcd : (xcd + 8), ob, pb);
    } else {
        const int q = slot - 84;
        const int b = xcd + 8 * (q / 56);
        const int h = q % 56;
        const int t = threadIdx.x;
        const int c0 = (t & 31) * 8;
        const int ws = t >> 5;                 // 0..7, covers w = ws*7..ws*7+6
        const float* ab2 = bnab + 3 * 512;
        const unsigned short* ab_base = avgin + (size_t)b * HW * CMID;

        // vertical 3-sum into LDS (f16)
        #pragma unroll
        for (int i = 0; i < 7; ++i) {
            int w = ws * 7 + i;
            float s[8];
            #pragma unroll
            for (int j = 0; j < 8; ++j) s[j] = 0.f;
            #pragma unroll
            for (int dh = -1; dh <= 1; ++dh) {
                int hh = h + dh;
                if ((unsigned)hh >= (unsigned)WDIM) continue;
                u16x8_t v = *(const u16x8_t*)(ab_base + (size_t)(hh * WDIM + w) * CMID + c0);
                #pragma unroll
                for (int j = 0; j < 8; ++j) s[j] += h2f(v[j]);
            }
            u16x8_t pk;
            #pragma unroll
            for (int j = 0; j < 8; ++j) pk[j] = f2h(s[j]);
            *(u16x8_t*)(smem + w * CMID + c0) = pk;
        }
        __syncthreads();

        // horizontal 3-sum + bn + scatter
        #pragma unroll
        for (int i = 0; i < 7; ++i) {
            int w = ws * 7 + i;
            float s[8];
            #pragma unroll
            for (int j = 0; j < 8; ++j) s[j] = 0.f;
            #pragma unroll
            for (int dw = -1; dw <= 1; ++dw) {
                int ww = w + dw;
                if ((unsigned)ww >= (unsigned)WDIM) continue;
                u16x8_t v = *(const u16x8_t*)(smem + ww * CMID + c0);
                #pragma unroll
                for (int j = 0; j < 8; ++j) s[j] += h2f(v[j]);
            }
            const int p = h * WDIM + w;
            #pragma unroll
            for (int j = 0; j < 8; ++j) {
                int c = c0 + j;
                int jc = 768 + c;
                int pos = pos_tab[jc];
                if (pos >= 0) {
                    float val = (s[j] * (1.f / 9.f)) * ab2[c] + ab2[256 + c];
                    out[((size_t)b * CFULL + pos) * HW + p] = val * scale_tab[jc];
                }
            }
        }
    }
}

// ---------------------------------------------------------------------------
// Launch
// ---------------------------------------------------------------------------
extern "C" void kernel_launch(void* const* d_in, const int* in_sizes, int n_in,
                              void* d_out, int out_size, void* d_ws, size_t ws_size,
                              hipStream_t stream) {
    (void)in_sizes; (void)n_in; (void)out_size; (void)ws_size;
    const float* x      = (const float*)d_in[0];
    const float* w_main = (const float*)d_in[1];
    const float* w_1x1  = (const float*)d_in[2];
    const float* w31    = (const float*)d_in[3];
    const float* bn31   = (const float*)d_in[4];
    const float* w33    = (const float*)d_in[5];
    const float* bn33   = (const float*)d_in[6];
    const float* wa1    = (const float*)d_in[7];
    const float* bna1   = (const float*)d_in[8];
    const float* bna2   = (const float*)d_in[9];
    const float* fw     = (const float*)d_in[10];
    const float* cscore = (const float*)d_in[11];
    float* out = (float*)d_out;

    char* ws = (char*)d_ws;
    unsigned short* x_nhwc = (unsigned short*)(ws);                 // 51,380,224 B
    unsigned short* u_nhwc = (unsigned short*)(ws + 51380224);      // 25,690,112 B
    unsigned short* avgin  = (unsigned short*)(ws + 77070336);      // 25,690,112 B
    unsigned short* Wcat   = (unsigned short*)(ws + 102760448);     //    786,432 B
    unsigned short* Wmain  = (unsigned short*)(ws + 103546880);     //  2,359,296 B
    unsigned short* W33r   = (unsigned short*)(ws + 105906176);     //  1,179,648 B
    float*          bnab   = (float*)        (ws + 107085824);      //      8,192 B
    int*            pos_tab= (int*)          (ws + 107094016);      //      4,096 B
    float*          scl_tab= (float*)        (ws + 107098112);      //      4,096 B

    dim3 blk(256);

    prep_tabs<<<dim3(1), dim3(1024), 0, stream>>>(cscore, bn31, bn33, bna1, bna2,
                                                  pos_tab, scl_tab, bnab);
    prep_weights<<<dim3(8448), blk, 0, stream>>>(w_main, w_1x1, w31, wa1, w33, fw,
                                                 Wcat, Wmain, W33r);
    transpose_x<<<dim3(49, 8, 16), blk, 0, stream>>>(x, x_nhwc);

    // K1: fused 1x1 (all batches) + main conv batches 0..7
    convK1<<<dim3(1568), blk, 0, stream>>>(x_nhwc, Wmain, Wcat, out,
                                           u_nhwc, avgin, bnab, pos_tab, scl_tab);

    // K2: main conv batches 8..15 + mid conv (all) + separable row-pool
    convK2<<<dim3(1568), blk, 0, stream>>>(x_nhwc, Wmain, u_nhwc, W33r, avgin,
                                           out, bnab, pos_tab, scl_tab);
}